// Round 9
// baseline (69.967 us; speedup 1.0000x reference)
//
#include <hip/hip_runtime.h>
#include <math.h>

// Bilateral filter, 5x5, reflect pad, sigma_spatial=2.0, sigma_range=0.1
// image: (16, 3, 512, 512) fp32 -> out same shape fp32.
//
// R9: exp -> LDS lookup table (move ~50% of issue load from the VALU/TRANS
// pipe to the idle DS pipe). Established by R6/R8: packed VALU ops are NOT
// faster per FLOP on CDNA4 (pk f16/f32 ~ 4 cyc/wave64), v_exp ~10 cyc, so
// R4's structure (~18 VALU-cyc per pixel-tap) was the VALU floor. Here:
//   t = 50*d^2 + r2/8, w = exp(-t) = tbl[round(t*64)]
//   window & center prescaled by SB = sqrt(12800) so that
//   m = fmaf(ds, ds, 32*r2 + 2.0f) IS the (rounded) byte offset of the
//   table entry; (int)m & ~3 -> ds_read_b32. Max m = 12800 + 258 < 16384
//   -> 4096-entry table, no clamp needed.
// Per pixel-tap: sub,fma,cvt,and,fma,add = 12 VALU cyc + 1 ds_read (DS pipe,
// overlapped across waves). Predicted ~3000 VALU cyc/wave vs R4's 4140.
// Table: 16 KB LDS/block -> 8 blocks/CU retained. Built once per block
// (256 thr x 16 exp2), input-independent -> deterministic.

#define IMG_H 512
#define IMG_W 512

__device__ __forceinline__ float frcp(float x) {
    return __builtin_amdgcn_rcpf(x);    // v_rcp_f32
}

// Each thread computes 8 contiguous x-pixels of one row of one (b,c) plane.
// tid bits: [5:0] = x-group (64 groups of 8), [14:6] = y (512), [..:15] = plane.
__global__ __launch_bounds__(256) void bilateral5x5_kernel(
        const float* __restrict__ img, float* __restrict__ out) {
    __shared__ float tbl[4096];   // tbl[i] = exp(-i/64)

    // build table: 256 threads x 16 entries
    {
        const int t0 = threadIdx.x * 16;
#pragma unroll
        for (int i = 0; i < 16; ++i) {
            const float idx = (float)(t0 + i);
            // exp(-idx/64) = 2^(-idx * log2(e)/64)
            tbl[t0 + i] = __builtin_amdgcn_exp2f(idx * -0.022539629859157305f);
        }
    }
    __syncthreads();

    const int tid = blockIdx.x * 256 + threadIdx.x;
    const int xg = tid & 63;
    const int y  = (tid >> 6) & 511;
    const int p  = tid >> 15;

    const float* __restrict__ plane = img + (size_t)p * (IMG_H * IMG_W);
    float* __restrict__ oplane      = out + (size_t)p * (IMG_H * IMG_W);
    const int x0 = xg << 3;

    // SB = sqrt(12800): ds = SB*(n-c) -> ds^2 = 12800*d^2 = byte offset of
    // 50*d^2 at 4 bytes per 1/64-of-t entry. +2 implements round-to-nearest.
    const float SB = 113.13708498984761f;

    // x-border (PAD=2): reflected cols land inside the central 8 ->
    // clamped in-bounds load addresses + 4 selects per row, no divergence.
    const bool xlo = (xg == 0);
    const bool xhi = (xg == 63);
    const int off_m0 = xlo ? x0 : (x0 - 4);
    const int off_m3 = xhi ? (x0 + 4) : (x0 + 8);

    // center pixels, prescaled by SB
    const float4 c1 = *reinterpret_cast<const float4*>(plane + (size_t)y * IMG_W + x0);
    const float4 c2 = *reinterpret_cast<const float4*>(plane + (size_t)y * IMG_W + x0 + 4);
    float cS[8];
    cS[0] = SB * c1.x; cS[1] = SB * c1.y; cS[2] = SB * c1.z; cS[3] = SB * c1.w;
    cS[4] = SB * c2.x; cS[5] = SB * c2.y; cS[6] = SB * c2.z; cS[7] = SB * c2.w;

    // center tap: w = 1 exactly
    float acc[8], nrm[8];
#pragma unroll
    for (int px = 0; px < 8; ++px) { acc[px] = cS[px]; nrm[px] = 1.0f; }

    const char* tbase = (const char*)tbl;

#pragma unroll
    for (int dy = -2; dy <= 2; ++dy) {
        int yy = y + dy;
        yy = (yy < 0) ? -yy : yy;                 // reflect top
        yy = (yy > 511) ? (1022 - yy) : yy;       // reflect bottom
        const float* __restrict__ row = plane + (size_t)yy * IMG_W;

        const float4 m0 = *reinterpret_cast<const float4*>(row + off_m0);
        const float4 m1 = *reinterpret_cast<const float4*>(row + x0);
        const float4 m2 = *reinterpret_cast<const float4*>(row + x0 + 4);
        const float4 m3 = *reinterpret_cast<const float4*>(row + off_m3);

        // window cols x0-2 .. x0+9, prescaled by SB
        const float w_m2 = xlo ? m1.z : m0.z;   // col -2 -> reflect col 2
        const float w_m1 = xlo ? m1.y : m0.w;   // col -1 -> reflect col 1
        const float w_8  = xhi ? m2.z : m3.x;   // col 512 -> reflect col 510
        const float w_9  = xhi ? m2.y : m3.y;   // col 513 -> reflect col 509

        float w[12];
        w[0]  = SB * w_m2;  w[1]  = SB * w_m1;
        w[2]  = SB * m1.x;  w[3]  = SB * m1.y;
        w[4]  = SB * m1.z;  w[5]  = SB * m1.w;
        w[6]  = SB * m2.x;  w[7]  = SB * m2.y;
        w[8]  = SB * m2.z;  w[9]  = SB * m2.w;
        w[10] = SB * w_8;   w[11] = SB * w_9;

#pragma unroll
        for (int dx = -2; dx <= 2; ++dx) {
            if (dy == 0 && dx == 0) continue;     // center handled above
            const int r2 = dy * dy + dx * dx;
            const float qb = (float)(32 * r2) + 2.0f;  // byte offset of spatial term (+2 = rounding)
#pragma unroll
            for (int px = 0; px < 8; ++px) {
                const float nn = w[px + dx + 2];
                const float d  = nn - cS[px];
                const float m  = fmaf(d, d, qb);      // byte offset + frac
                const int  ib  = ((int)m) & ~3;       // 4-aligned, < 16384
                const float wt = *(const float*)(tbase + ib);   // ds_read_b32
                acc[px] = fmaf(wt, nn, acc[px]);
                nrm[px] += wt;
            }
        }
    }

    // acc = SB * sum(w*n); out = acc * rcp(SB*nrm + SB*1e-8)
    const float Seps = SB * 1e-8f;
    float4 o1, o2;
    o1.x = acc[0] * frcp(fmaf(nrm[0], SB, Seps));
    o1.y = acc[1] * frcp(fmaf(nrm[1], SB, Seps));
    o1.z = acc[2] * frcp(fmaf(nrm[2], SB, Seps));
    o1.w = acc[3] * frcp(fmaf(nrm[3], SB, Seps));
    o2.x = acc[4] * frcp(fmaf(nrm[4], SB, Seps));
    o2.y = acc[5] * frcp(fmaf(nrm[5], SB, Seps));
    o2.z = acc[6] * frcp(fmaf(nrm[6], SB, Seps));
    o2.w = acc[7] * frcp(fmaf(nrm[7], SB, Seps));
    *reinterpret_cast<float4*>(oplane + (size_t)y * IMG_W + x0)     = o1;
    *reinterpret_cast<float4*>(oplane + (size_t)y * IMG_W + x0 + 4) = o2;
}

extern "C" void kernel_launch(void* const* d_in, const int* in_sizes, int n_in,
                              void* d_out, int out_size, void* d_ws, size_t ws_size,
                              hipStream_t stream) {
    const float* img = (const float*)d_in[0];
    float* out = (float*)d_out;

    const int n = in_sizes[0];                 // 16*3*512*512 = 12,582,912
    const int threads = n / 8;                 // 8 pixels per thread
    const int block = 256;
    const int grid = threads / block;          // 6144

    bilateral5x5_kernel<<<grid, block, 0, stream>>>(img, out);
}